// Round 16
// baseline (351.089 us; speedup 1.0000x reference)
//
#include <hip/hip_runtime.h>

#define H    50
#define T    65536
#define NTHREADS 256
#define KCHUNK   512          // 2 blocks/CU (waves_per_eu(2,2) -> 2 waves/SIMD)
#define CLEN     (T / KCHUNK) // 128 output steps per block
#define WARM     64           // unchanged from R15 (verified)

// ws layout (floats)
#define WC1_OFF 0        // 200*64
#define WC2_OFF 12800    // 200*128

typedef float v2f __attribute__((ext_vector_type(2)));
typedef float v4f __attribute__((ext_vector_type(4)));

// Prep (unchanged): permute rows (r' = j*4+gate), pad cols, fold biases into
// cols 58 (Wc1) / 100 (Wc2).
__global__ void prep_kernel(const float* __restrict__ Wih1, const float* __restrict__ Whh1,
                            const float* __restrict__ bih1, const float* __restrict__ bhh1,
                            const float* __restrict__ Wih2, const float* __restrict__ Whh2,
                            const float* __restrict__ bih2, const float* __restrict__ bhh2,
                            float* __restrict__ ws) {
  int idx = blockIdx.x * blockDim.x + threadIdx.x;
  if (idx < 200 * 64) {
    int nr = idx >> 6, c = idx & 63;
    int j = nr >> 2, gate = nr & 3, r = gate * 50 + j;
    float v = 0.f;
    if (c < 8) v = Wih1[r * 8 + c];
    else if (c < 58) v = Whh1[r * 50 + (c - 8)];
    else if (c == 58) v = bih1[r] + bhh1[r];
    ws[WC1_OFF + idx] = v;
  }
  if (idx < 200 * 128) {
    int nr = idx >> 7, c = idx & 127;
    int j = nr >> 2, gate = nr & 3, r = gate * 50 + j;
    float v = 0.f;
    if (c < 50) v = Wih2[r * 50 + c];
    else if (c < 100) v = Whh2[r * 50 + (c - 50)];
    else if (c == 100) v = bih2[r] + bhh2[r];
    ws[WC2_OFF + idx] = v;
  }
}

__device__ __forceinline__ float sigm(float x) {
  return __builtin_amdgcn_rcpf(1.f + __expf(-x));
}
__device__ __forceinline__ float tanh_(float x) {
  return 1.f - 2.f * __builtin_amdgcn_rcpf(1.f + __expf(2.f * x));
}
__device__ __forceinline__ void bar() {
  asm volatile("s_waitcnt lgkmcnt(0)\n\ts_barrier" ::: "memory");
}
// 0xB1=qp xor1 ; 0x4E=qp xor2 ; 0x141=row_half_mirror (8-lane) ; 0x140=row_mirror
template<int CTRL>
__device__ __forceinline__ float dpp_add(float x) {
  int y = __builtin_amdgcn_mov_dpp(__float_as_int(x), CTRL, 0xF, 0xF, true);
  return x + __int_as_float(y);
}
__device__ __forceinline__ float rdlane(float v, int lane) {
  return __int_as_float(__builtin_amdgcn_readlane(__float_as_int(v), lane));
}
// logical col -> chunk-padded LDS word: 16-float chunks at stride 20
// (8 slice start-addrs hit disjoint bank quads -> conflict-free; R5-verified)
__device__ __forceinline__ int phys(int c) { return (c >> 4) * 20 + (c & 15); }

// ============================================================================
// R16 = R15's chunked 2-phase schedule with COLUMN-SLICED matvecs (R5's
// verified geometry). R15 diagnosis: 2 blocks/CU is LDS-pipe-bound — 26
// broadcast ds_read_b128 per wave per step x 8 waves ~ 2400cy = the whole
// 1.24us step. Column-slicing: group g=tid>>3 owns rows 8g..8g+7; slice
// p=tid&7 reads 16 cols of CIN=[h1|h2|1] (4 b128) + 8 cols of AIN=[x|0|h1|1]
// (2 b128); register weights; 3-dpp reduce -> group-uniform sums; owner lanes
// (p=0,4) do gates2. y-reduce OFF-chain: per-wave partial -> WYP[4]; wave0
// reads 4 floats at phase-1 head. LDS instr/CU/step ~240 -> ~80.
// ============================================================================

__launch_bounds__(NTHREADS)
__attribute__((amdgpu_waves_per_eu(2, 2)))
__global__ void lstm_kernel(const float* __restrict__ xseq,
                            const float* __restrict__ ws,
                            const float* __restrict__ Wout,
                            const float* __restrict__ bout,
                            float* __restrict__ out) {
  // CIN logical 128: [h1(50) | h2(50) | 1.0@100 | 0] chunk-padded -> 160
  // AIN logical 64 : [x(7) | 0@7 | h1@8..57 | 1.0@58 | 0] chunk-padded -> 80
  __shared__ __align__(16) float CIN[2][160];
  __shared__ __align__(16) float AIN[2][80];
  __shared__ __align__(16) float PART[2][256];  // gates1 rows (sans err)
  __shared__ __align__(16) float WYP[4];        // per-wave y partials
  __shared__ float ACT4[4];                     // act_dist ring, depth 4

  const int tid = threadIdx.x;
  const int g   = tid >> 3;                     // row group (rows 8g..8g+7)
  const int p   = tid & 7;                      // column slice
  const int cbase = p * 5;                      // CIN float4 idx of 16-col slice
  const int abase = 5 * (p >> 1) + 2 * (p & 1); // AIN float4 idx of 8-col slice
  const int pm  = 2 * g + (p & 1);              // PART quad idx (writers p<2)
  const bool own2 = ((tid & 3) == 0) && (tid < 200);
  const int h2off = phys(50 + ((tid >> 2) & 63));
  const int h1cOff = phys(tid & 63);
  const int h1aOff = phys(8 + (tid & 63));

  const int sk   = blockIdx.x * CLEN;
  const int t0   = (sk >= WARM) ? (sk - WARM) : 0;
  const int tend = sk + CLEN - 1;

  const float* Wc1 = ws + WC1_OFF;
  const float* Wc2 = ws + WC2_OFF;

  // ---- register weights (sliced): W2[8 rows][8 v2f]=128f, W1[8][4]=64f ----
  const v2f z2 = {0.f, 0.f};
  v2f W2[8][8], W1[8][4];
  #pragma unroll
  for (int k = 0; k < 8; k++) {
    #pragma unroll
    for (int q = 0; q < 8; q++) W2[k][q] = z2;
    #pragma unroll
    for (int q = 0; q < 4; q++) W1[k][q] = z2;
  }
  if (tid < 200) {
    #pragma unroll
    for (int k = 0; k < 8; k++) {
      const float* r2 = &Wc2[(8 * g + k) * 128 + 16 * p];
      #pragma unroll
      for (int q = 0; q < 8; q++) { W2[k][q].x = r2[2*q]; W2[k][q].y = r2[2*q+1]; }
      const float* r1 = &Wc1[(8 * g + k) * 64 + 8 * p];
      #pragma unroll
      for (int q = 0; q < 4; q++) { W1[k][q].x = r1[2*q]; W1[k][q].y = r1[2*q+1]; }
    }
  }
  float wo = 0.f;
  if (own2) wo = Wout[(tid >> 2)];              // owner unit uo=tid>>2 < 50
  const float bo  = bout[0];
  const float mbo = -0.1f * bo;
  float we0 = 0.f, we1 = 0.f, we2 = 0.f, we3 = 0.f;
  if (tid < 50) {                                // wave-0 gates1 role
    we0 = Wc1[(4 * tid + 0) * 64 + 7];
    we1 = Wc1[(4 * tid + 1) * 64 + 7];
    we2 = Wc1[(4 * tid + 2) * 64 + 7];
    we3 = Wc1[(4 * tid + 3) * 64 + 7];
  }

  float c1 = 0.f, c2 = 0.f, errv = 0.f, E = 0.f, xr = 0.f;
  const int par0 = t0 & 1;

  // ---- LDS init ----
  for (int i = tid; i < 2 * 160; i += NTHREADS) ((float*)CIN)[i]  = 0.f;
  for (int i = tid; i < 2 * 80;  i += NTHREADS) ((float*)AIN)[i]  = 0.f;
  for (int i = tid; i < 2 * 256; i += NTHREADS) ((float*)PART)[i] = 0.f;
  if (tid < 4) { WYP[tid] = 0.f; ACT4[tid] = 0.f; }
  __syncthreads();
  if (tid == 0) {
    CIN[0][124] = 1.f; CIN[1][124] = 1.f;       // phys(100) bias col
    AIN[0][70]  = 1.f; AIN[1][70]  = 1.f;       // phys(58)  bias col
  }
  if (tid < 7)                AIN[par0 ^ 1][tid]      = xseq[t0 * 8 + tid];       // x(t0) (priming)
  if (tid >= 16 && tid < 23)  AIN[par0][tid - 16]     = xseq[(t0 + 1) * 8 + tid - 16]; // x(t0+1)
  if (tid == 8)  ACT4[t0 & 3]       = xseq[t0 * 8 + 7];
  if (tid == 9)  ACT4[(t0 + 1) & 3] = xseq[(t0 + 1) * 8 + 7];
  if (tid >= 248) xr = xseq[(t0 + 2) * 8 + (tid - 248)];
  __syncthreads();

#define CELL1_SLICED(AINbuf, PARTdst) {                                \
    const v4f* AU = (const v4f*)(AINbuf);                              \
    v4f ua = AU[abase];                                                \
    v4f ub = AU[abase + 1];                                            \
    v2f alo = __builtin_shufflevector(ua, ua, 0, 1);                   \
    v2f ahi = __builtin_shufflevector(ua, ua, 2, 3);                   \
    v2f blo = __builtin_shufflevector(ub, ub, 0, 1);                   \
    v2f bhi = __builtin_shufflevector(ub, ub, 2, 3);                   \
    float bsum[8];                                                     \
    _Pragma("unroll")                                                  \
    for (int k = 0; k < 8; k++) {                                      \
      v2f acc = W1[k][0] * alo;                                        \
      acc += W1[k][1] * ahi;                                           \
      acc += W1[k][2] * blo;                                           \
      acc += W1[k][3] * bhi;                                           \
      bsum[k] = acc.x + acc.y;                                         \
      bsum[k] = dpp_add<0xB1>(bsum[k]);                                \
      bsum[k] = dpp_add<0x4E>(bsum[k]);                                \
      bsum[k] = dpp_add<0x141>(bsum[k]);                               \
    }                                                                  \
    if (tid < 200 && p < 2) {                                          \
      float4 pv;                                                       \
      pv.x = p ? bsum[4] : bsum[0]; pv.y = p ? bsum[5] : bsum[1];      \
      pv.z = p ? bsum[6] : bsum[2]; pv.w = p ? bsum[7] : bsum[3];      \
      *(float4*)&(PARTdst)[4 * pm] = pv;                               \
    } }

  // ---- priming: PART[par0] = W1 * [x(t0); 0; h1=0; 1]  (spec state 0) ----
  CELL1_SLICED(AIN[par0 ^ 1], PART[par0])
  __syncthreads();

  #pragma unroll 1
  for (int t = t0; t <= tend; t++) {
    const int par = t & 1;
    // =============== PHASE 1 ===============
    if (tid < 64) {                              // wave 0: y, err, gates1
      float4 wyp = *(const float4*)WYP;
      float acta = ACT4[t & 3];
      float yraw = (wyp.x + wyp.y) + (wyp.z + wyp.w);
      if (tid == 0 && t > sk) out[t - 1] = yraw + bo;
      errv = E - 0.1f * yraw;                    // err(t-1)
      E = fmaf(0.9f, errv, fmaf(0.1f, acta, mbo));
      if (tid < 50) {
        float4 pq = *(const float4*)&PART[par][4 * tid];
        float gi = sigm (fmaf(we0, errv, pq.x));
        float gf = sigm (fmaf(we1, errv, pq.y));
        float gg = tanh_(fmaf(we2, errv, pq.z));
        float go = sigm (fmaf(we3, errv, pq.w));
        c1 = gf * c1 + gi * gg;
        float h1 = go * tanh_(c1);
        CIN[par][h1cOff] = h1;                   // for cell-2 (this step)
        AIN[par][h1aOff] = h1;                   // for cell-1 (this step)
      }
    } else if (tid >= 248) {                     // loader (wave 3)
      int c = tid - 248;
      if (c < 7) AIN[par ^ 1][c] = xr; else ACT4[(t + 2) & 3] = xr;
      int nt = (t + 3 < T) ? t + 3 : T - 1;
      xr = xseq[nt * 8 + c];
    }
    bar();                                        // #1: h1 ready
    // =============== PHASE 2 (sliced matvecs) ===============
    float wyv = 0.f;
    {
      const v4f* CU = (const v4f*)CIN[par];
      v2f acc[8];
      #pragma unroll
      for (int k = 0; k < 8; k++) acc[k] = z2;
      #pragma unroll
      for (int s = 0; s < 4; s++) {
        v4f h4 = CU[cbase + s];
        v2f lo = __builtin_shufflevector(h4, h4, 0, 1);
        v2f hi = __builtin_shufflevector(h4, h4, 2, 3);
        #pragma unroll
        for (int k = 0; k < 8; k++) {
          acc[k] += W2[k][2 * s] * lo;           // v_pk_fma_f32
          acc[k] += W2[k][2 * s + 1] * hi;
        }
      }
      float asum[8];
      #pragma unroll
      for (int k = 0; k < 8; k++) {
        asum[k] = acc[k].x + acc[k].y;
        asum[k] = dpp_add<0xB1>(asum[k]);
        asum[k] = dpp_add<0x4E>(asum[k]);
        asum[k] = dpp_add<0x141>(asum[k]);
      }
      if (own2) {                                // p in {0,4}: unit tid>>2
        float s0 = (tid & 4) ? asum[4] : asum[0];
        float s1 = (tid & 4) ? asum[5] : asum[1];
        float sg = (tid & 4) ? asum[6] : asum[2];
        float s3 = (tid & 4) ? asum[7] : asum[3];
        float gi = sigm(s0), gf = sigm(s1), gg = tanh_(sg), go = sigm(s3);
        c2 = gf * c2 + gi * gg;
        float h2v = go * tanh_(c2);
        CIN[par ^ 1][h2off] = h2v;               // h2(t) for step t+1
        wyv = wo * h2v;
      }
    }
    CELL1_SLICED(AIN[par], PART[par ^ 1])        // PART(t+1)
    {                                            // off-chain y partials
      float v = wyv;
      v = dpp_add<0xB1>(v); v = dpp_add<0x4E>(v);
      v = dpp_add<0x141>(v); v = dpp_add<0x140>(v);
      float tot = (rdlane(v, 0) + rdlane(v, 16)) +
                  (rdlane(v, 32) + rdlane(v, 48));
      if ((tid & 63) == 0) WYP[tid >> 6] = tot;
    }
    bar();                                        // #2
  }
  // ---- epilogue: y(tend) from WYP (written at step tend phase 2) ----
  if (tid == 0) {
    float4 wyp = *(const float4*)WYP;
    out[tend] = (wyp.x + wyp.y) + (wyp.z + wyp.w) + bo;
  }
}

extern "C" void kernel_launch(void* const* d_in, const int* in_sizes, int n_in,
                              void* d_out, int out_size, void* d_ws, size_t ws_size,
                              hipStream_t stream) {
  const float* xseq = (const float*)d_in[0];
  const float* Wih1 = (const float*)d_in[1];
  const float* Whh1 = (const float*)d_in[2];
  const float* bih1 = (const float*)d_in[3];
  const float* bhh1 = (const float*)d_in[4];
  const float* Wih2 = (const float*)d_in[5];
  const float* Whh2 = (const float*)d_in[6];
  const float* bih2 = (const float*)d_in[7];
  const float* bhh2 = (const float*)d_in[8];
  const float* Wout = (const float*)d_in[9];
  const float* bout = (const float*)d_in[10];
  float* ws = (float*)d_ws;

  prep_kernel<<<100, 256, 0, stream>>>(Wih1, Whh1, bih1, bhh1,
                                       Wih2, Whh2, bih2, bhh2, ws);
  lstm_kernel<<<KCHUNK, NTHREADS, 0, stream>>>(xseq, ws, Wout, bout, (float*)d_out);
}